// Round 1
// baseline (2392.645 us; speedup 1.0000x reference)
//
#include <hip/hip_runtime.h>

// ---------------------------------------------------------------------------
// GCN 5-layer forward on MI355X.
// Pipeline per call:
//   1) build CSR (incoming edges per dst) in workspace
//   2) per layer: GEMM (h = act @ W) then CSR aggregation with
//      symmetric normalization + self-loop + bias + ReLU (layers 1..4)
// ---------------------------------------------------------------------------

static const int GCN_DIMS[6] = {512, 200, 175, 125, 75, 50};

__global__ void zero_kernel(int* __restrict__ p, int n) {
    int i = blockIdx.x * blockDim.x + threadIdx.x;
    for (; i < n; i += gridDim.x * blockDim.x) p[i] = 0;
}

__global__ void hist_kernel(const int* __restrict__ dst, int E, int* __restrict__ deg) {
    int i = blockIdx.x * blockDim.x + threadIdx.x;
    for (; i < E; i += gridDim.x * blockDim.x) atomicAdd(&deg[dst[i]], 1);
}

// Single-block hierarchical exclusive scan of deg[0..N) -> rowptr[0..N]
__global__ __launch_bounds__(1024) void scan_kernel(const int* __restrict__ deg,
                                                    int* __restrict__ rowptr, int N) {
    __shared__ int sums[1024];
    int t = threadIdx.x;
    int chunk = (N + 1023) >> 10;
    int lo = t * chunk;
    int hi = lo + chunk; if (hi > N) hi = N;
    if (lo > N) lo = N;
    int s = 0;
    for (int i = lo; i < hi; ++i) s += deg[i];
    sums[t] = s;
    __syncthreads();
    for (int off = 1; off < 1024; off <<= 1) {
        int v = (t >= off) ? sums[t - off] : 0;
        __syncthreads();
        sums[t] += v;
        __syncthreads();
    }
    int run = (t > 0) ? sums[t - 1] : 0;
    for (int i = lo; i < hi; ++i) { rowptr[i] = run; run += deg[i]; }
    if (t == 1023) rowptr[N] = run;
}

__global__ void dinv_kernel(const int* __restrict__ deg, float* __restrict__ dinv, int N) {
    int i = blockIdx.x * blockDim.x + threadIdx.x;
    for (; i < N; i += gridDim.x * blockDim.x)
        dinv[i] = rsqrtf((float)(deg[i] + 1));  // +1 for self loop
}

__global__ void copy_kernel(const int* __restrict__ a, int* __restrict__ b, int n) {
    int i = blockIdx.x * blockDim.x + threadIdx.x;
    for (; i < n; i += gridDim.x * blockDim.x) b[i] = a[i];
}

__global__ void scatter_kernel(const int* __restrict__ src, const int* __restrict__ dst,
                               int E, int* __restrict__ cursor, int* __restrict__ csrc) {
    int i = blockIdx.x * blockDim.x + threadIdx.x;
    for (; i < E; i += gridDim.x * blockDim.x) {
        int d = dst[i];
        int pos = atomicAdd(&cursor[d], 1);
        csrc[pos] = src[i];
    }
}

// fp32 tiled GEMM: C[M,N] = A[M,K] @ B[K,N].  64x64 tile, BK=16, 4x4/thread.
__global__ __launch_bounds__(256) void gemm_kernel(const float* __restrict__ A,
                                                   const float* __restrict__ B,
                                                   float* __restrict__ C,
                                                   int M, int K, int N) {
    __shared__ float As[16][68];  // [k][m], padded to keep b128 reads aligned
    __shared__ float Bs[16][64];  // [k][n]

    int tid = threadIdx.x;
    int tx = tid & 15;       // output col group
    int ty = tid >> 4;       // output row group
    int m0 = blockIdx.x * 64;
    int n0 = blockIdx.y * 64;

    int am = tid >> 2;          // 0..63  (row within tile for A load)
    int ak = (tid & 3) * 4;     // 0,4,8,12
    int bk = tid >> 4;          // 0..15  (k row for B load)
    int bn = (tid & 15) * 4;    // 0..60

    bool arow_ok = (m0 + am) < M;
    const float* Arow = A + (size_t)(m0 + am) * K;

    float acc[4][4];
#pragma unroll
    for (int i = 0; i < 4; ++i)
#pragma unroll
        for (int j = 0; j < 4; ++j) acc[i][j] = 0.f;

    for (int k0 = 0; k0 < K; k0 += 16) {
#pragma unroll
        for (int i = 0; i < 4; ++i) {
            int kk = k0 + ak + i;
            As[ak + i][am] = (arow_ok && kk < K) ? Arow[kk] : 0.f;
        }
#pragma unroll
        for (int i = 0; i < 4; ++i) {
            int nn = n0 + bn + i;
            int kk = k0 + bk;
            Bs[bk][bn + i] = (kk < K && nn < N) ? B[(size_t)kk * N + nn] : 0.f;
        }
        __syncthreads();
#pragma unroll
        for (int k = 0; k < 16; ++k) {
            float a[4], bb[4];
#pragma unroll
            for (int i = 0; i < 4; ++i) a[i] = As[k][ty * 4 + i];
#pragma unroll
            for (int j = 0; j < 4; ++j) bb[j] = Bs[k][tx * 4 + j];
#pragma unroll
            for (int i = 0; i < 4; ++i)
#pragma unroll
                for (int j = 0; j < 4; ++j) acc[i][j] = fmaf(a[i], bb[j], acc[i][j]);
        }
        __syncthreads();
    }

#pragma unroll
    for (int i = 0; i < 4; ++i) {
        int m = m0 + ty * 4 + i;
        if (m >= M) continue;
#pragma unroll
        for (int j = 0; j < 4; ++j) {
            int n = n0 + tx * 4 + j;
            if (n < N) C[(size_t)m * N + n] = acc[i][j];
        }
    }
}

// CSR aggregation: out[i][f] = relu( dinv[i]*( dinv[i]*h[i][f] +
//                  sum_{s in in(i)} dinv[s]*h[s][f] ) + bias[f] )
__global__ void agg_kernel(const float* __restrict__ h, const int* __restrict__ rowptr,
                           const int* __restrict__ csrc, const float* __restrict__ dinv,
                           const float* __restrict__ bias, float* __restrict__ out,
                           int N, int D, int do_relu) {
    int node = blockIdx.x;
    if (node >= N) return;
    int f = threadIdx.x;
    if (f >= D) return;

    float di = dinv[node];
    int beg = rowptr[node];
    int end = rowptr[node + 1];

    float acc = di * h[(size_t)node * D + f];  // self loop (norm = di*di)
    for (int j = beg; j < end; ++j) {
        int s = csrc[j];
        acc += dinv[s] * h[(size_t)s * D + f];
    }
    float v = fmaf(di, acc, bias[f]);
    if (do_relu) v = fmaxf(v, 0.f);
    out[(size_t)node * D + f] = v;
}

extern "C" void kernel_launch(void* const* d_in, const int* in_sizes, int n_in,
                              void* d_out, int out_size, void* d_ws, size_t ws_size,
                              hipStream_t stream) {
    const float* x = (const float*)d_in[0];
    const int* ei = (const int*)d_in[1];
    int E = in_sizes[1] / 2;
    int N = in_sizes[0] / GCN_DIMS[0];
    const int* src = ei;
    const int* dst = ei + E;

    const float* W[5];
    const float* bia[5];
    for (int i = 0; i < 5; ++i) {
        W[i] = (const float*)d_in[2 + 2 * i];
        bia[i] = (const float*)d_in[3 + 2 * i];
    }

    char* ws = (char*)d_ws;
    size_t off = 0;
    auto alloc = [&](size_t bytes) -> void* {
        void* p = ws + off;
        off += (bytes + 255) & ~(size_t)255;
        return p;
    };
    int* deg = (int*)alloc((size_t)N * 4);
    int* rowptr = (int*)alloc((size_t)(N + 1) * 4);
    int* cursor = (int*)alloc((size_t)N * 4);
    float* dinv = (float*)alloc((size_t)N * 4);
    int* csrc = (int*)alloc((size_t)E * 4);
    float* bufH = (float*)alloc((size_t)N * 200 * 4);
    float* bufA = (float*)alloc((size_t)N * 200 * 4);
    (void)ws_size;

    // ---- graph preprocessing ----
    zero_kernel<<<1024, 256, 0, stream>>>(deg, N);
    hist_kernel<<<2048, 256, 0, stream>>>(dst, E, deg);
    scan_kernel<<<1, 1024, 0, stream>>>(deg, rowptr, N);
    dinv_kernel<<<512, 256, 0, stream>>>(deg, dinv, N);
    copy_kernel<<<512, 256, 0, stream>>>(rowptr, cursor, N);
    scatter_kernel<<<2048, 256, 0, stream>>>(src, dst, E, cursor, csrc);

    // ---- layers ----
    const float* in = x;
    for (int l = 0; l < 5; ++l) {
        int K = GCN_DIMS[l];
        int D = GCN_DIMS[l + 1];
        dim3 grid((N + 63) / 64, (D + 63) / 64);
        gemm_kernel<<<grid, 256, 0, stream>>>(in, W[l], bufH, N, K, D);
        float* outp = (l == 4) ? (float*)d_out : bufA;
        int blk = ((D + 63) / 64) * 64;
        agg_kernel<<<N, blk, 0, stream>>>(bufH, rowptr, csrc, dinv, bia[l], outp, N, D,
                                          (l < 4) ? 1 : 0);
        in = bufA;
    }
    (void)out_size; (void)n_in;
}

// Round 2
// 1513.577 us; speedup vs baseline: 1.5808x; 1.5808x over previous
//
#include <hip/hip_runtime.h>
#include <hip/hip_bf16.h>

// ---------------------------------------------------------------------------
// GCN 5-layer forward on MI355X (gfx950).
//   - CSR build (incoming edges per dst) in workspace
//   - per layer: split-bf16 MFMA GEMM (h = act @ W), then CSR aggregation
//     with symmetric norm + self loop + bias + ReLU (layers 1..4)
// Padded feature dims (mult of 32): 512, 224, 192, 128, 96, 64.
// ---------------------------------------------------------------------------

typedef float f32x4 __attribute__((ext_vector_type(4)));
typedef short bf16x8 __attribute__((ext_vector_type(8)));

static const int GDIMS[6] = {512, 200, 175, 125, 75, 50};
static const int GPAD[6]  = {512, 224, 192, 128, 96, 64};

// ---------------- graph preprocessing ----------------

__global__ void zero_kernel(int* __restrict__ p, int n) {
    int i = blockIdx.x * blockDim.x + threadIdx.x;
    for (; i < n; i += gridDim.x * blockDim.x) p[i] = 0;
}

__global__ void hist_kernel(const int* __restrict__ dst, int E, int* __restrict__ deg) {
    int i = blockIdx.x * blockDim.x + threadIdx.x;
    for (; i < E; i += gridDim.x * blockDim.x) atomicAdd(&deg[dst[i]], 1);
}

__global__ __launch_bounds__(1024) void scan_kernel(const int* __restrict__ deg,
                                                    int* __restrict__ rowptr, int N) {
    __shared__ int sums[1024];
    int t = threadIdx.x;
    int chunk = (N + 1023) >> 10;
    int lo = t * chunk;
    int hi = lo + chunk; if (hi > N) hi = N;
    if (lo > N) lo = N;
    int s = 0;
    for (int i = lo; i < hi; ++i) s += deg[i];
    sums[t] = s;
    __syncthreads();
    for (int off = 1; off < 1024; off <<= 1) {
        int v = (t >= off) ? sums[t - off] : 0;
        __syncthreads();
        sums[t] += v;
        __syncthreads();
    }
    int run = (t > 0) ? sums[t - 1] : 0;
    for (int i = lo; i < hi; ++i) { rowptr[i] = run; run += deg[i]; }
    if (t == 1023) rowptr[N] = run;
}

__global__ void dinv_kernel(const int* __restrict__ deg, float* __restrict__ dinv, int N) {
    int i = blockIdx.x * blockDim.x + threadIdx.x;
    for (; i < N; i += gridDim.x * blockDim.x)
        dinv[i] = rsqrtf((float)(deg[i] + 1));  // +1 self loop
}

__global__ void copy_kernel(const int* __restrict__ a, int* __restrict__ b, int n) {
    int i = blockIdx.x * blockDim.x + threadIdx.x;
    for (; i < n; i += gridDim.x * blockDim.x) b[i] = a[i];
}

__global__ void scatter_kernel(const int* __restrict__ src, const int* __restrict__ dst,
                               int E, int* __restrict__ cursor, int* __restrict__ csrc) {
    int i = blockIdx.x * blockDim.x + threadIdx.x;
    for (; i < E; i += gridDim.x * blockDim.x) {
        int d = dst[i];
        int pos = atomicAdd(&cursor[d], 1);
        csrc[pos] = src[i];
    }
}

// ---------------- weight pre-transpose + split ----------------
// W [K][Nout] fp32 -> Whi/Wlo [NB][Kp] bf16 (zero padded)

__global__ void wsplit_kernel(const float* __restrict__ W, int K, int Nout,
                              int Kp, ushort* __restrict__ Whi, ushort* __restrict__ Wlo) {
    int k = blockIdx.x * blockDim.x + threadIdx.x;
    int n = blockIdx.y;
    if (k >= Kp) return;
    float v = (k < K && n < Nout) ? W[(size_t)k * Nout + n] : 0.f;
    __bf16 h = (__bf16)v;
    float hf = (float)h;
    __bf16 l = (__bf16)(v - hf);
    Whi[(size_t)n * Kp + k] = __builtin_bit_cast(ushort, h);
    Wlo[(size_t)n * Kp + k] = __builtin_bit_cast(ushort, l);
}

// ---------------- split-bf16 MFMA GEMM ----------------
// C[Mp][Pout] = A[Mrows][lda] @ Wt^T  (Wt stored [n][k] bf16 hi/lo)
// block: 256 threads = 4 waves, each wave owns 64 rows x 64 cols.
// grid: (Mp/256, ceil(Pout/64))

__device__ inline f32x4 mfma16(bf16x8 a, bf16x8 b, f32x4 c) {
    return __builtin_amdgcn_mfma_f32_16x16x32_bf16(a, b, c, 0, 0, 0);
}

__device__ inline void split_frag(f32x4 a0, f32x4 a1, bf16x8& hi, bf16x8& lo) {
    float af[8];
    af[0] = a0[0]; af[1] = a0[1]; af[2] = a0[2]; af[3] = a0[3];
    af[4] = a1[0]; af[5] = a1[1]; af[6] = a1[2]; af[7] = a1[3];
#pragma unroll
    for (int e = 0; e < 8; ++e) {
        __bf16 h = (__bf16)af[e];
        float hf = (float)h;
        __bf16 l = (__bf16)(af[e] - hf);
        hi[e] = __builtin_bit_cast(short, h);
        lo[e] = __builtin_bit_cast(short, l);
    }
}

__global__ __launch_bounds__(256) void gemm_mfma(
    const float* __restrict__ A, int lda, int Mrows,
    const ushort* __restrict__ Bhi, const ushort* __restrict__ Blo, int Kp,
    float* __restrict__ C, int ldc, int Pout)
{
    int lane = threadIdx.x & 63;
    int wave = threadIdx.x >> 6;
    int m0 = blockIdx.x * 256 + wave * 64;
    int n0 = blockIdx.y * 64;
    int koff = (lane >> 4) * 8;   // k sub-offset per 16-lane group

    const float* aptr[4];
#pragma unroll
    for (int fm = 0; fm < 4; ++fm) {
        int row = m0 + fm * 16 + (lane & 15);
        if (row > Mrows - 1) row = Mrows - 1;   // clamp (tail block only)
        aptr[fm] = A + (size_t)row * lda + koff;
    }
    const ushort* bhp[4];
#pragma unroll
    for (int fn = 0; fn < 4; ++fn) {
        int n = n0 + fn * 16 + (lane & 15);
        bhp[fn] = Bhi + (size_t)n * Kp + koff;
    }
    size_t lo_off = (size_t)(Blo - Bhi);

    f32x4 acc[4][4];
#pragma unroll
    for (int i = 0; i < 4; ++i)
#pragma unroll
        for (int j = 0; j < 4; ++j) acc[i][j] = (f32x4)0.f;

    for (int k0 = 0; k0 < Kp; k0 += 32) {
        bf16x8 vbh[4], vbl[4];
#pragma unroll
        for (int fn = 0; fn < 4; ++fn) {
            vbh[fn] = *(const bf16x8*)(bhp[fn] + k0);
            vbl[fn] = *(const bf16x8*)(bhp[fn] + lo_off + k0);
        }
        bf16x8 vah[4], val[4];
#pragma unroll
        for (int fm = 0; fm < 4; ++fm) {
            f32x4 a0 = *(const f32x4*)(aptr[fm] + k0);
            f32x4 a1 = *(const f32x4*)(aptr[fm] + k0 + 4);
            split_frag(a0, a1, vah[fm], val[fm]);
        }
#pragma unroll
        for (int fm = 0; fm < 4; ++fm)
#pragma unroll
            for (int fn = 0; fn < 4; ++fn) {
                acc[fm][fn] = mfma16(vah[fm], vbh[fn], acc[fm][fn]);
                acc[fm][fn] = mfma16(vah[fm], vbl[fn], acc[fm][fn]);
                acc[fm][fn] = mfma16(val[fm], vbh[fn], acc[fm][fn]);
            }
    }

    // store: lane holds D[(lane>>4)*4+r][lane&15] per fragment
#pragma unroll
    for (int fm = 0; fm < 4; ++fm) {
#pragma unroll
        for (int fn = 0; fn < 4; ++fn) {
            int col = n0 + fn * 16 + (lane & 15);
            if (col < Pout) {
#pragma unroll
                for (int r = 0; r < 4; ++r) {
                    int row = m0 + fm * 16 + (lane >> 4) * 4 + r;
                    C[(size_t)row * ldc + col] = acc[fm][fn][r];
                }
            }
        }
    }
}

// ---------------- CSR aggregation (vectorized) ----------------
// out[i][f] = relu( dinv[i]*( dinv[i]*h[i][f] + sum_s dinv[s]*h[s][f] ) + b[f] )
// L lanes per node (power of 2), each lane one float4 column group.

__global__ __launch_bounds__(256) void agg_kernel(
    const float* __restrict__ h, int ldh,
    const int* __restrict__ rowptr, const int* __restrict__ csrc,
    const float* __restrict__ dinv, const float* __restrict__ bias,
    int D, int N, int Mp, float* __restrict__ out, int ldo,
    int L, int relu, int final_layer)
{
    int tid = threadIdx.x;
    int node = blockIdx.x * (256 / L) + tid / L;
    if (node >= Mp) return;
    int f4 = tid & (L - 1);
    int ld4 = ldh >> 2;
    bool act = f4 < ld4;

    const f32x4* h4 = (const f32x4*)h;
    f32x4 acc = (f32x4)0.f;
    float di = 0.f;
    if (node < N) {
        di = dinv[node];
        if (act) acc = di * h4[(size_t)node * ld4 + f4];
        int beg = rowptr[node];
        int end = rowptr[node + 1];
        for (int j = beg; j < end; ++j) {
            int s = csrc[j];
            float ds = dinv[s];
            if (act) acc += ds * h4[(size_t)s * ld4 + f4];
        }
    }

    if (final_layer) {
        if (node >= N) return;
#pragma unroll
        for (int e = 0; e < 4; ++e) {
            int f = f4 * 4 + e;
            if (f < D) out[(size_t)node * ldo + f] = fmaf(di, acc[e], bias[f]);
        }
    } else {
        if (!act) return;
        f32x4 v;
#pragma unroll
        for (int e = 0; e < 4; ++e) {
            int f = f4 * 4 + e;
            float val = 0.f;
            if (node < N && f < D) {
                val = fmaf(di, acc[e], bias[f]);
                if (relu) val = fmaxf(val, 0.f);
            }
            v[e] = val;
        }
        *(f32x4*)(out + (size_t)node * ldo + f4 * 4) = v;
    }
}

// ---------------- host launcher ----------------

extern "C" void kernel_launch(void* const* d_in, const int* in_sizes, int n_in,
                              void* d_out, int out_size, void* d_ws, size_t ws_size,
                              hipStream_t stream) {
    const float* x = (const float*)d_in[0];
    const int* ei = (const int*)d_in[1];
    int E = in_sizes[1] / 2;
    int N = in_sizes[0] / GDIMS[0];
    int Mp = ((N + 255) / 256) * 256;
    const int* src = ei;
    const int* dst = ei + E;

    const float* W[5];
    const float* bia[5];
    for (int i = 0; i < 5; ++i) {
        W[i] = (const float*)d_in[2 + 2 * i];
        bia[i] = (const float*)d_in[3 + 2 * i];
    }

    char* ws = (char*)d_ws;
    size_t off = 0;
    auto alloc = [&](size_t bytes) -> void* {
        void* p = ws + off;
        off += (bytes + 255) & ~(size_t)255;
        return p;
    };
    int* deg = (int*)alloc((size_t)N * 4);
    int* rowptr = (int*)alloc((size_t)(N + 1) * 4);
    int* cursor = (int*)alloc((size_t)N * 4);
    float* dinv = (float*)alloc((size_t)N * 4);
    int* csrc = (int*)alloc((size_t)E * 4);
    float* buf0 = (float*)alloc((size_t)Mp * 224 * 4);
    float* buf1 = (float*)alloc((size_t)Mp * 224 * 4);
    ushort* Whi[5];
    ushort* Wlo[5];
    int NB[5];
    for (int l = 0; l < 5; ++l) {
        int Kp = GPAD[l];
        NB[l] = ((GPAD[l + 1] + 63) / 64) * 64;
        Whi[l] = (ushort*)alloc((size_t)NB[l] * Kp * 2);
        Wlo[l] = (ushort*)alloc((size_t)NB[l] * Kp * 2);
    }
    (void)ws_size;

    // graph preprocessing
    zero_kernel<<<1024, 256, 0, stream>>>(deg, N);
    hist_kernel<<<2048, 256, 0, stream>>>(dst, E, deg);
    scan_kernel<<<1, 1024, 0, stream>>>(deg, rowptr, N);
    dinv_kernel<<<512, 256, 0, stream>>>(deg, dinv, N);
    copy_kernel<<<512, 256, 0, stream>>>(rowptr, cursor, N);
    scatter_kernel<<<2048, 256, 0, stream>>>(src, dst, E, cursor, csrc);

    // weight split
    for (int l = 0; l < 5; ++l) {
        int Kp = GPAD[l];
        dim3 g((Kp + 255) / 256, NB[l]);
        wsplit_kernel<<<g, 256, 0, stream>>>(W[l], GDIMS[l], GDIMS[l + 1], Kp,
                                             Whi[l], Wlo[l]);
    }

    // layers
    for (int l = 0; l < 5; ++l) {
        int Kp = GPAD[l];
        int Pout = GPAD[l + 1];
        int D = GDIMS[l + 1];
        const float* Ain = (l == 0) ? x : buf1;
        int lda = Kp;                       // GPAD[0]==512 for layer 0
        int Mrows = (l == 0) ? N : Mp;

        dim3 gg(Mp / 256, (Pout + 63) / 64);
        gemm_mfma<<<gg, 256, 0, stream>>>(Ain, lda, Mrows, Whi[l], Wlo[l], Kp,
                                          buf0, Pout, Pout);

        int ld4 = Pout / 4;
        int L = (ld4 > 32) ? 64 : (ld4 > 16) ? 32 : 16;
        int nodes_per_block = 256 / L;
        int blocks = (Mp + nodes_per_block - 1) / nodes_per_block;
        if (l == 4) {
            agg_kernel<<<blocks, 256, 0, stream>>>(buf0, Pout, rowptr, csrc, dinv,
                                                   bia[l], D, N, Mp, (float*)d_out, D,
                                                   L, 0, 1);
        } else {
            agg_kernel<<<blocks, 256, 0, stream>>>(buf0, Pout, rowptr, csrc, dinv,
                                                   bia[l], D, N, Mp, buf1, Pout,
                                                   L, 1, 0);
        }
    }
    (void)out_size; (void)n_in;
}

// Round 3
// 1293.706 us; speedup vs baseline: 1.8495x; 1.1700x over previous
//
#include <hip/hip_runtime.h>
#include <hip/hip_bf16.h>

// ---------------------------------------------------------------------------
// GCN 5-layer forward on MI355X (gfx950).
//   - CSR build (incoming edges per dst)
//   - per layer: split-bf16 MFMA GEMM with LDS-shared A staging, epilogue
//     scales rows by dinv (g = dinv*h, zero for pad rows)
//   - aggregation: out = dinv[i]*(g[i] + sum_s g[s]) + bias (+ReLU)
// Padded feature dims: 512, 224, 192, 128, 96, 64.
// ---------------------------------------------------------------------------

typedef float f32x4 __attribute__((ext_vector_type(4)));
typedef short bf16x8 __attribute__((ext_vector_type(8)));

static const int GDIMS[6] = {512, 200, 175, 125, 75, 50};
static const int GPAD[6]  = {512, 224, 192, 128, 96, 64};

// ---------------- graph preprocessing ----------------

__global__ void zero_kernel(int* __restrict__ p, int n) {
    int i = blockIdx.x * blockDim.x + threadIdx.x;
    for (; i < n; i += gridDim.x * blockDim.x) p[i] = 0;
}

__global__ void hist_kernel(const int* __restrict__ dst, int E, int* __restrict__ deg) {
    int i = blockIdx.x * blockDim.x + threadIdx.x;
    for (; i < E; i += gridDim.x * blockDim.x) atomicAdd(&deg[dst[i]], 1);
}

__global__ __launch_bounds__(1024) void scan_kernel(const int* __restrict__ deg,
                                                    int* __restrict__ rowptr, int N) {
    __shared__ int sums[1024];
    int t = threadIdx.x;
    int chunk = (N + 1023) >> 10;
    int lo = t * chunk;
    int hi = lo + chunk; if (hi > N) hi = N;
    if (lo > N) lo = N;
    int s = 0;
    for (int i = lo; i < hi; ++i) s += deg[i];
    sums[t] = s;
    __syncthreads();
    for (int off = 1; off < 1024; off <<= 1) {
        int v = (t >= off) ? sums[t - off] : 0;
        __syncthreads();
        sums[t] += v;
        __syncthreads();
    }
    int run = (t > 0) ? sums[t - 1] : 0;
    for (int i = lo; i < hi; ++i) { rowptr[i] = run; run += deg[i]; }
    if (t == 1023) rowptr[N] = run;
}

__global__ void dinv_kernel(const int* __restrict__ deg, float* __restrict__ dinv, int N) {
    int i = blockIdx.x * blockDim.x + threadIdx.x;
    for (; i < N; i += gridDim.x * blockDim.x)
        dinv[i] = rsqrtf((float)(deg[i] + 1));  // +1 self loop
}

__global__ void copy_kernel(const int* __restrict__ a, int* __restrict__ b, int n) {
    int i = blockIdx.x * blockDim.x + threadIdx.x;
    for (; i < n; i += gridDim.x * blockDim.x) b[i] = a[i];
}

__global__ void scatter_kernel(const int* __restrict__ src, const int* __restrict__ dst,
                               int E, int* __restrict__ cursor, int* __restrict__ csrc) {
    int i = blockIdx.x * blockDim.x + threadIdx.x;
    for (; i < E; i += gridDim.x * blockDim.x) {
        int d = dst[i];
        int pos = atomicAdd(&cursor[d], 1);
        csrc[pos] = src[i];
    }
}

// ---------------- weight pre-transpose + split ----------------

__global__ void wsplit_kernel(const float* __restrict__ W, int K, int Nout,
                              int Kp, ushort* __restrict__ Whi, ushort* __restrict__ Wlo) {
    int k = blockIdx.x * blockDim.x + threadIdx.x;
    int n = blockIdx.y;
    if (k >= Kp) return;
    float v = (k < K && n < Nout) ? W[(size_t)k * Nout + n] : 0.f;
    __bf16 h = (__bf16)v;
    ushort hb = __builtin_bit_cast(ushort, h);
    float hf = __builtin_bit_cast(float, (unsigned)hb << 16);
    __bf16 l = (__bf16)(v - hf);
    Whi[(size_t)n * Kp + k] = hb;
    Wlo[(size_t)n * Kp + k] = __builtin_bit_cast(ushort, l);
}

// ---------------- split-bf16 MFMA GEMM ----------------

__device__ inline f32x4 mfma16(bf16x8 a, bf16x8 b, f32x4 c) {
    return __builtin_amdgcn_mfma_f32_16x16x32_bf16(a, b, c, 0, 0, 0);
}

__device__ inline void split8(f32x4 a0, f32x4 a1, bf16x8& hi, bf16x8& lo) {
    float af[8] = {a0[0], a0[1], a0[2], a0[3], a1[0], a1[1], a1[2], a1[3]};
#pragma unroll
    for (int e = 0; e < 8; ++e) {
        __bf16 h = (__bf16)af[e];
        ushort hb = __builtin_bit_cast(ushort, h);
        float hf = __builtin_bit_cast(float, (unsigned)hb << 16);
        __bf16 l = (__bf16)(af[e] - hf);
        hi[e] = (short)hb;
        lo[e] = __builtin_bit_cast(short, l);
    }
}

// Block tile: (WM*64) rows x (WN*64) cols, K-step 32, one block covers the
// full output width (grid.y == 1). A staged via LDS as split bf16 (shared
// conversion). Epilogue scales each row by dinv[row] (0 for row >= N).
template<int WM, int WN>
__global__ __launch_bounds__(WM * WN * 64) void gemm_t(
    const float* __restrict__ A, int lda, int Arows,
    const ushort* __restrict__ Bhi, const ushort* __restrict__ Blo, int Kp,
    const float* __restrict__ dinv, int N,
    float* __restrict__ C, int ldc)
{
    constexpr int BM = WM * 64;
    constexpr int T = WM * WN * 64;
    constexpr int SROW = BM + 2;          // kg-stride pad: write conflicts <= 2-way
    __shared__ ushort Ah[4 * SROW * 8];
    __shared__ ushort Al[4 * SROW * 8];

    const int tid = threadIdx.x;
    const int lane = tid & 63;
    const int wave = tid >> 6;
    const int wm = (WM == 1) ? 0 : (wave % WM);
    const int wn = (WM == 1) ? wave : (wave / WM);
    const int m0 = blockIdx.x * BM;
    const int kg = lane >> 4;
    const int l16 = lane & 15;

    const ushort* bp[4];
#pragma unroll
    for (int fn = 0; fn < 4; ++fn) {
        int n = wn * 64 + fn * 16 + l16;
        bp[fn] = Bhi + (size_t)n * Kp + kg * 8;
    }
    const size_t lo_off = (size_t)(Blo - Bhi);

    f32x4 acc[4][4];
#pragma unroll
    for (int i = 0; i < 4; ++i)
#pragma unroll
        for (int j = 0; j < 4; ++j) acc[i][j] = (f32x4)0.f;

    for (int k0 = 0; k0 < Kp; k0 += 32) {
        // stage A[BM x 32] -> LDS split bf16 (coalesced 128B per 4 lanes)
        for (int j = tid; j < BM * 4; j += T) {
            int row = j >> 2, jk = j & 3;
            int gr = m0 + row; if (gr > Arows - 1) gr = Arows - 1;
            const float* ap = A + (size_t)gr * lda + k0 + jk * 8;
            f32x4 a0 = *(const f32x4*)ap;
            f32x4 a1 = *(const f32x4*)(ap + 4);
            bf16x8 hi, lo;
            split8(a0, a1, hi, lo);
            int idx = (jk * SROW + row) * 8;
            *(bf16x8*)&Ah[idx] = hi;
            *(bf16x8*)&Al[idx] = lo;
        }
        __syncthreads();

        bf16x8 bh[4], bl[4], ah[4], al[4];
#pragma unroll
        for (int fn = 0; fn < 4; ++fn) {
            bh[fn] = *(const bf16x8*)(bp[fn] + k0);
            bl[fn] = *(const bf16x8*)(bp[fn] + lo_off + k0);
        }
#pragma unroll
        for (int fm = 0; fm < 4; ++fm) {
            int idx = (kg * SROW + wm * 64 + fm * 16 + l16) * 8;
            ah[fm] = *(const bf16x8*)&Ah[idx];
            al[fm] = *(const bf16x8*)&Al[idx];
        }
#pragma unroll
        for (int fm = 0; fm < 4; ++fm)
#pragma unroll
            for (int fn = 0; fn < 4; ++fn) {
                acc[fm][fn] = mfma16(ah[fm], bh[fn], acc[fm][fn]);
                acc[fm][fn] = mfma16(ah[fm], bl[fn], acc[fm][fn]);
                acc[fm][fn] = mfma16(al[fm], bh[fn], acc[fm][fn]);
            }
        __syncthreads();
    }

    float dv[4][4];
#pragma unroll
    for (int fm = 0; fm < 4; ++fm)
#pragma unroll
        for (int r = 0; r < 4; ++r) {
            int row = m0 + wm * 64 + fm * 16 + kg * 4 + r;
            dv[fm][r] = (row < N) ? dinv[row] : 0.f;
        }
#pragma unroll
    for (int fm = 0; fm < 4; ++fm)
#pragma unroll
        for (int fn = 0; fn < 4; ++fn) {
            int col = wn * 64 + fn * 16 + l16;
            if (col < ldc) {
#pragma unroll
                for (int r = 0; r < 4; ++r) {
                    int row = m0 + wm * 64 + fm * 16 + kg * 4 + r;
                    C[(size_t)row * ldc + col] = acc[fm][fn][r] * dv[fm][r];
                }
            }
        }
}

// ---------------- CSR aggregation ----------------
// out[i][f] = relu( dinv[i]*(g[i][f] + sum_s g[s][f]) + b[f] ), g = dinv*h.
// L lanes per node; lane = one float4 column group; edge loop unrolled x4.

template<int L>
__global__ __launch_bounds__(256) void agg_t(
    const float* __restrict__ g, int ldg, int nd4,
    const int* __restrict__ rowptr, const int* __restrict__ csrc,
    const float* __restrict__ dinv, const float* __restrict__ bias,
    int D, int N, float* __restrict__ out, int ldo, int relu, int fin)
{
    int node = blockIdx.x * (256 / L) + threadIdx.x / L;
    if (node >= N) return;
    int f4 = threadIdx.x & (L - 1);
    if (f4 >= nd4) return;

    const f32x4* g4 = (const f32x4*)g;
    int ld4 = ldg >> 2;
    f32x4 a0 = g4[(size_t)node * ld4 + f4];   // self term
    f32x4 a1 = (f32x4)0.f, a2 = (f32x4)0.f, a3 = (f32x4)0.f;
    int beg = rowptr[node], end = rowptr[node + 1];
    int j = beg;
    for (; j + 3 < end; j += 4) {
        int s0 = csrc[j], s1 = csrc[j + 1], s2 = csrc[j + 2], s3 = csrc[j + 3];
        a0 += g4[(size_t)s0 * ld4 + f4];
        a1 += g4[(size_t)s1 * ld4 + f4];
        a2 += g4[(size_t)s2 * ld4 + f4];
        a3 += g4[(size_t)s3 * ld4 + f4];
    }
    for (; j < end; ++j) a0 += g4[(size_t)csrc[j] * ld4 + f4];

    f32x4 s = (a0 + a1) + (a2 + a3);
    float di = dinv[node];
    if (fin) {
#pragma unroll
        for (int e = 0; e < 4; ++e) {
            int f = f4 * 4 + e;
            if (f < D) out[(size_t)node * ldo + f] = fmaf(di, s[e], bias[f]);
        }
    } else {
        f32x4 v;
#pragma unroll
        for (int e = 0; e < 4; ++e) {
            int f = f4 * 4 + e;
            float val = (f < D) ? fmaf(di, s[e], bias[f]) : 0.f;
            if (relu) val = fmaxf(val, 0.f);
            v[e] = val;
        }
        *(f32x4*)(out + (size_t)node * ldo + f4 * 4) = v;
    }
}

// ---------------- host launcher ----------------

extern "C" void kernel_launch(void* const* d_in, const int* in_sizes, int n_in,
                              void* d_out, int out_size, void* d_ws, size_t ws_size,
                              hipStream_t stream) {
    const float* x = (const float*)d_in[0];
    const int* ei = (const int*)d_in[1];
    int E = in_sizes[1] / 2;
    int N = in_sizes[0] / GDIMS[0];
    int Mp = ((N + 255) / 256) * 256;
    const int* src = ei;
    const int* dst = ei + E;

    const float* W[5];
    const float* bia[5];
    for (int i = 0; i < 5; ++i) {
        W[i] = (const float*)d_in[2 + 2 * i];
        bia[i] = (const float*)d_in[3 + 2 * i];
    }

    char* ws = (char*)d_ws;
    size_t off = 0;
    auto alloc = [&](size_t bytes) -> void* {
        void* p = ws + off;
        off += (bytes + 255) & ~(size_t)255;
        return p;
    };
    int* deg = (int*)alloc((size_t)N * 4);
    int* rowptr = (int*)alloc((size_t)(N + 1) * 4);
    int* cursor = (int*)alloc((size_t)N * 4);
    float* dinv = (float*)alloc((size_t)N * 4);
    int* csrc = (int*)alloc((size_t)E * 4);
    float* buf0 = (float*)alloc((size_t)Mp * 224 * 4);
    float* buf1 = (float*)alloc((size_t)Mp * 224 * 4);
    ushort* Whi[5];
    ushort* Wlo[5];
    int NB[5];
    for (int l = 0; l < 5; ++l) {
        int Kp = GPAD[l];
        NB[l] = ((GPAD[l + 1] + 63) / 64) * 64;
        if (l == 0) NB[l] = 256;  // (1,4) reads 256 cols
        Whi[l] = (ushort*)alloc((size_t)NB[l] * Kp * 2);
        Wlo[l] = (ushort*)alloc((size_t)NB[l] * Kp * 2);
    }
    // layer 3 uses (2,2): reads 128 cols, NB[3]=128 ok (ceil(96/64)*64 = 128)
    (void)ws_size;

    // graph preprocessing
    zero_kernel<<<1024, 256, 0, stream>>>(deg, N);
    hist_kernel<<<2048, 256, 0, stream>>>(dst, E, deg);
    scan_kernel<<<1, 1024, 0, stream>>>(deg, rowptr, N);
    dinv_kernel<<<512, 256, 0, stream>>>(deg, dinv, N);
    copy_kernel<<<512, 256, 0, stream>>>(rowptr, cursor, N);
    scatter_kernel<<<2048, 256, 0, stream>>>(src, dst, E, cursor, csrc);

    // weight split
    for (int l = 0; l < 5; ++l) {
        int Kp = GPAD[l];
        dim3 gw((Kp + 255) / 256, NB[l]);
        wsplit_kernel<<<gw, 256, 0, stream>>>(W[l], GDIMS[l], GDIMS[l + 1], Kp,
                                              Whi[l], Wlo[l]);
    }

    // layers
    for (int l = 0; l < 5; ++l) {
        int Kp = GPAD[l];
        int Pout = GPAD[l + 1];
        int D = GDIMS[l + 1];
        const float* Ain = (l == 0) ? x : buf1;
        int lda = GPAD[l];

        if (l == 0) {
            gemm_t<1, 4><<<Mp / 64, 256, 0, stream>>>(Ain, lda, N, Whi[l], Wlo[l], Kp,
                                                      dinv, N, buf0, Pout);
        } else if (l == 1) {
            gemm_t<1, 3><<<Mp / 64, 192, 0, stream>>>(Ain, lda, N, Whi[l], Wlo[l], Kp,
                                                      dinv, N, buf0, Pout);
        } else if (l == 2 || l == 3) {
            gemm_t<2, 2><<<Mp / 128, 256, 0, stream>>>(Ain, lda, N, Whi[l], Wlo[l], Kp,
                                                       dinv, N, buf0, Pout);
        } else {
            gemm_t<4, 1><<<Mp / 256, 256, 0, stream>>>(Ain, lda, N, Whi[l], Wlo[l], Kp,
                                                       dinv, N, buf0, Pout);
        }

        int nd4 = (D + 3) / 4;
        float* outp = (l == 4) ? (float*)d_out : buf1;
        int ldo = (l == 4) ? D : Pout;
        int relu = (l < 4) ? 1 : 0;
        int fin = (l == 4) ? 1 : 0;
        if (l <= 1) {
            int npb = 256 / 64;
            agg_t<64><<<(N + npb - 1) / npb, 256, 0, stream>>>(buf0, Pout, nd4, rowptr,
                                                               csrc, dinv, bia[l], D, N,
                                                               outp, ldo, relu, fin);
        } else if (l <= 3) {
            int npb = 256 / 32;
            agg_t<32><<<(N + npb - 1) / npb, 256, 0, stream>>>(buf0, Pout, nd4, rowptr,
                                                               csrc, dinv, bia[l], D, N,
                                                               outp, ldo, relu, fin);
        } else {
            int npb = 256 / 16;
            agg_t<16><<<(N + npb - 1) / npb, 256, 0, stream>>>(buf0, Pout, nd4, rowptr,
                                                               csrc, dinv, bia[l], D, N,
                                                               outp, ldo, relu, fin);
        }
    }
    (void)out_size; (void)n_in;
}